// Round 2
// baseline (1562.384 us; speedup 1.0000x reference)
//
#include <hip/hip_runtime.h>

#define BATCH 256
#define TLEN  512
#define DIN   64
#define HID   128
#define NOUT  40

typedef _Float16 h2_t __attribute__((ext_vector_type(2)));

static __device__ __forceinline__ unsigned pack_h2(float a, float b) {
    h2_t v; v[0] = (_Float16)a; v[1] = (_Float16)b;
    return __builtin_bit_cast(unsigned, v);
}

static __device__ __forceinline__ float fdot2(unsigned a, unsigned b, float c) {
#if __has_builtin(__builtin_amdgcn_fdot2)
    return __builtin_amdgcn_fdot2(__builtin_bit_cast(h2_t, a),
                                  __builtin_bit_cast(h2_t, b), c, false);
#else
    h2_t x = __builtin_bit_cast(h2_t, a), y = __builtin_bit_cast(h2_t, b);
    return fmaf((float)x[1], (float)y[1], fmaf((float)x[0], (float)y[0], c));
#endif
}

static __device__ __forceinline__ float sigmoidf_(float x) {
    return 1.0f / (1.0f + __expf(-x));
}
static __device__ __forceinline__ float tanhf_(float x) {
    float ax = fabsf(x);
    float e  = __expf(-2.0f * ax);      // in (0,1], never overflows
    float t  = (1.0f - e) / (1.0f + e);
    return copysignf(t, x);
}

// ---------------- Layer 0 ----------------
// 1024 threads / block, one block per batch element.
// Threads (2g, 2g+1) split gate g's dot product over K-halves; combine via shfl.
// Per-thread weights: wx 16 regs (packed f16) + wh 64 regs (f32) -> no spill at 128 cap.
__global__ __launch_bounds__(1024, 4) void lstm_l0(
    const float* __restrict__ x,
    const float* __restrict__ Wih, const float* __restrict__ Whh,
    const float* __restrict__ bih, const float* __restrict__ bhh,
    float* __restrict__ hstate, float* __restrict__ cstate,
    _Float16* __restrict__ y0, int t0, int t1)
{
    const int b   = blockIdx.x;
    const int tid = threadIdx.x;
    const int g   = tid >> 1;     // gate row 0..511
    const int p   = tid & 1;      // K-half

    __shared__ __align__(16) unsigned xs[2][DIN / 2];   // packed f16 pairs, double-buffered
    __shared__ __align__(16) float    hlds[HID];
    __shared__ __align__(16) float    gact[4 * HID];    // activated gates

    unsigned wx[DIN / 4];   // 16 packed pairs = 32 x-weights
    float    wh[HID / 2];   // 64 f32 h-weights
    {
        const float4* wr = reinterpret_cast<const float4*>(Wih + (size_t)g * DIN + p * (DIN / 2));
        #pragma unroll
        for (int q = 0; q < DIN / 8; ++q) {
            float4 v = wr[q];
            wx[2 * q]     = pack_h2(v.x, v.y);
            wx[2 * q + 1] = pack_h2(v.z, v.w);
        }
        const float4* wr2 = reinterpret_cast<const float4*>(Whh + (size_t)g * HID + p * (HID / 2));
        #pragma unroll
        for (int q = 0; q < HID / 8; ++q) {
            float4 v = wr2[q];
            wh[4 * q] = v.x; wh[4 * q + 1] = v.y; wh[4 * q + 2] = v.z; wh[4 * q + 3] = v.w;
        }
    }
    const float bias = (p == 0) ? (bih[g] + bhh[g]) : 0.f;

    float c = 0.f;
    if (tid < HID) {
        c = cstate[b * HID + tid];
        hlds[tid] = hstate[b * HID + tid];
    }

    // x loaders: threads 128..143, one float4 (4 values) each; distance-2 prefetch
    const float4* xrow = reinterpret_cast<const float4*>(x + (size_t)b * TLEN * DIN);
    const int lk = tid - 128;
    float4 xpre = make_float4(0.f, 0.f, 0.f, 0.f);
    if (lk >= 0 && lk < 16) {
        float4 v = xrow[(size_t)t0 * (DIN / 4) + lk];
        xs[0][2 * lk]     = pack_h2(v.x, v.y);
        xs[0][2 * lk + 1] = pack_h2(v.z, v.w);
        if (t0 + 1 < TLEN) xpre = xrow[(size_t)(t0 + 1) * (DIN / 4) + lk];
    }
    __syncthreads();

    for (int t = t0; t < t1; ++t) {
        const int rel = t - t0;
        float acc = bias;
        const uint4* xv = reinterpret_cast<const uint4*>(&xs[rel & 1][p * (DIN / 4)]);
        #pragma unroll
        for (int q = 0; q < DIN / 16; ++q) {            // 4 x uint4 = 16 pairs
            uint4 v = xv[q];
            acc = fdot2(wx[4 * q + 0], v.x, acc);
            acc = fdot2(wx[4 * q + 1], v.y, acc);
            acc = fdot2(wx[4 * q + 2], v.z, acc);
            acc = fdot2(wx[4 * q + 3], v.w, acc);
        }
        const float4* hv = reinterpret_cast<const float4*>(&hlds[p * (HID / 2)]);
        #pragma unroll
        for (int q = 0; q < HID / 8; ++q) {             // 16 x float4 = 64 values
            float4 v = hv[q];
            acc = fmaf(wh[4 * q + 0], v.x, acc);
            acc = fmaf(wh[4 * q + 1], v.y, acc);
            acc = fmaf(wh[4 * q + 2], v.z, acc);
            acc = fmaf(wh[4 * q + 3], v.w, acc);
        }
        float full = acc + __shfl_xor(acc, 1);

        // issue next-next x load (lands during the following step)
        float4 xnext = make_float4(0.f, 0.f, 0.f, 0.f);
        if (lk >= 0 && lk < 16 && t + 2 < TLEN) xnext = xrow[(size_t)(t + 2) * (DIN / 4) + lk];

        if (p == 0) {
            float a = (g < 2 * HID) ? sigmoidf_(full)
                     : (g < 3 * HID) ? tanhf_(full)
                                     : sigmoidf_(full);
            gact[g] = a;
        }
        __syncthreads();

        if (tid < HID) {
            float iv = gact[tid], fv = gact[tid + HID];
            float gv = gact[tid + 2 * HID], ov = gact[tid + 3 * HID];
            c = fmaf(fv, c, iv * gv);
            float h = ov * tanhf_(c);
            hlds[tid] = h;
            y0[((size_t)rel * BATCH + b) * HID + tid] = (_Float16)h;
        }
        if (lk >= 0 && lk < 16) {
            xs[(rel + 1) & 1][2 * lk]     = pack_h2(xpre.x, xpre.y);
            xs[(rel + 1) & 1][2 * lk + 1] = pack_h2(xpre.z, xpre.w);
            xpre = xnext;
        }
        __syncthreads();
    }
    if (tid < HID) {
        cstate[b * HID + tid] = c;
        hstate[b * HID + tid] = hlds[tid];
    }
}

// ---------------- Layer 1 ----------------
// Same structure; input is the f16 y0 chunk (already packed pairs).
// Per-thread weights: wx 32 + wh 64 = 96 regs.
__global__ __launch_bounds__(1024, 4) void lstm_l1(
    const _Float16* __restrict__ y0,
    const float* __restrict__ Wih, const float* __restrict__ Whh,
    const float* __restrict__ bih, const float* __restrict__ bhh,
    float* __restrict__ hstate, float* __restrict__ cstate,
    int t0, int t1)
{
    const int b   = blockIdx.x;
    const int tid = threadIdx.x;
    const int g   = tid >> 1;
    const int p   = tid & 1;

    __shared__ __align__(16) unsigned ys[2][HID / 2];   // 64 packed pairs
    __shared__ __align__(16) float    hlds[HID];
    __shared__ __align__(16) float    gact[4 * HID];

    unsigned wx[HID / 4];   // 32 packed pairs = 64 y-weights
    float    wh[HID / 2];   // 64 f32
    {
        const float4* wr = reinterpret_cast<const float4*>(Wih + (size_t)g * HID + p * (HID / 2));
        #pragma unroll
        for (int q = 0; q < HID / 8; ++q) {
            float4 v = wr[q];
            wx[2 * q]     = pack_h2(v.x, v.y);
            wx[2 * q + 1] = pack_h2(v.z, v.w);
        }
        const float4* wr2 = reinterpret_cast<const float4*>(Whh + (size_t)g * HID + p * (HID / 2));
        #pragma unroll
        for (int q = 0; q < HID / 8; ++q) {
            float4 v = wr2[q];
            wh[4 * q] = v.x; wh[4 * q + 1] = v.y; wh[4 * q + 2] = v.z; wh[4 * q + 3] = v.w;
        }
    }
    const float bias = (p == 0) ? (bih[g] + bhh[g]) : 0.f;

    float c = 0.f;
    if (tid < HID) {
        c = cstate[b * HID + tid];
        hlds[tid] = hstate[b * HID + tid];
    }

    // y0 loaders: threads 128..143, one uint4 (8 f16) each; distance-2 prefetch
    const uint4* yrow = reinterpret_cast<const uint4*>(y0);
    const int lk = tid - 128;
    uint4 ypre = make_uint4(0u, 0u, 0u, 0u);
    if (lk >= 0 && lk < 16) {
        uint4 v = yrow[((size_t)0 * BATCH + b) * (HID / 8) + lk];
        reinterpret_cast<uint4*>(&ys[0][0])[lk] = v;
        if (t0 + 1 < t1) ypre = yrow[((size_t)1 * BATCH + b) * (HID / 8) + lk];
    }
    __syncthreads();

    for (int t = t0; t < t1; ++t) {
        const int rel = t - t0;
        float acc = bias;
        const uint4* yv = reinterpret_cast<const uint4*>(&ys[rel & 1][p * (HID / 4)]);
        #pragma unroll
        for (int q = 0; q < HID / 16; ++q) {            // 8 x uint4 = 32 pairs
            uint4 v = yv[q];
            acc = fdot2(wx[4 * q + 0], v.x, acc);
            acc = fdot2(wx[4 * q + 1], v.y, acc);
            acc = fdot2(wx[4 * q + 2], v.z, acc);
            acc = fdot2(wx[4 * q + 3], v.w, acc);
        }
        const float4* hv = reinterpret_cast<const float4*>(&hlds[p * (HID / 2)]);
        #pragma unroll
        for (int q = 0; q < HID / 8; ++q) {
            float4 v = hv[q];
            acc = fmaf(wh[4 * q + 0], v.x, acc);
            acc = fmaf(wh[4 * q + 1], v.y, acc);
            acc = fmaf(wh[4 * q + 2], v.z, acc);
            acc = fmaf(wh[4 * q + 3], v.w, acc);
        }
        float full = acc + __shfl_xor(acc, 1);

        uint4 ynext = make_uint4(0u, 0u, 0u, 0u);
        if (lk >= 0 && lk < 16 && t + 2 < t1)
            ynext = yrow[((size_t)(rel + 2) * BATCH + b) * (HID / 8) + lk];

        if (p == 0) {
            float a = (g < 2 * HID) ? sigmoidf_(full)
                     : (g < 3 * HID) ? tanhf_(full)
                                     : sigmoidf_(full);
            gact[g] = a;
        }
        __syncthreads();

        if (tid < HID) {
            float iv = gact[tid], fv = gact[tid + HID];
            float gv = gact[tid + 2 * HID], ov = gact[tid + 3 * HID];
            c = fmaf(fv, c, iv * gv);
            float h = ov * tanhf_(c);
            hlds[tid] = h;
        }
        if (lk >= 0 && lk < 16) {
            reinterpret_cast<uint4*>(&ys[(rel + 1) & 1][0])[lk] = ypre;
            ypre = ynext;
        }
        __syncthreads();
    }
    if (tid < HID) {
        cstate[b * HID + tid] = c;
        hstate[b * HID + tid] = hlds[tid];
    }
}

// ---------------- Final FC ----------------
__global__ __launch_bounds__(128) void fc_kernel(
    const float* __restrict__ h1, const float* __restrict__ Wfc,
    const float* __restrict__ bfc, float* __restrict__ out)
{
    const int b = blockIdx.x;
    const int o = threadIdx.x;
    __shared__ float hs[HID];
    hs[o] = h1[b * HID + o];
    __syncthreads();
    if (o < NOUT) {
        const float4* w  = reinterpret_cast<const float4*>(Wfc + (size_t)o * HID);
        const float4* hv = reinterpret_cast<const float4*>(hs);
        float acc = bfc[o];
        #pragma unroll
        for (int q = 0; q < HID / 4; ++q) {
            float4 wv = w[q]; float4 h4 = hv[q];
            acc = fmaf(wv.x, h4.x, fmaf(wv.y, h4.y, fmaf(wv.z, h4.z, fmaf(wv.w, h4.w, acc))));
        }
        out[b * NOUT + o] = acc;
    }
}

extern "C" void kernel_launch(void* const* d_in, const int* in_sizes, int n_in,
                              void* d_out, int out_size, void* d_ws, size_t ws_size,
                              hipStream_t stream) {
    const float* x    = (const float*)d_in[0];
    const float* Wih0 = (const float*)d_in[1];
    const float* Whh0 = (const float*)d_in[2];
    const float* bih0 = (const float*)d_in[3];
    const float* bhh0 = (const float*)d_in[4];
    const float* Wih1 = (const float*)d_in[5];
    const float* Whh1 = (const float*)d_in[6];
    const float* bih1 = (const float*)d_in[7];
    const float* bhh1 = (const float*)d_in[8];
    const float* Wfc  = (const float*)d_in[9];
    const float* bfc  = (const float*)d_in[10];
    float* out = (float*)d_out;

    // Workspace: h0, c0, h1, c1 (f32) then y0 chunk slab (f16)
    float* h0 = (float*)d_ws;
    float* c0 = h0 + BATCH * HID;
    float* h1 = c0 + BATCH * HID;
    float* c1 = h1 + BATCH * HID;
    _Float16* y0 = (_Float16*)(c1 + BATCH * HID);

    const size_t stateBytes = (size_t)4 * BATCH * HID * sizeof(float);   // 512 KB
    size_t avail = ws_size > stateBytes ? ws_size - stateBytes : 0;
    int Tc = (int)(avail / ((size_t)BATCH * HID * sizeof(_Float16)));
    if (Tc > TLEN) Tc = TLEN;
    if (Tc < 1) Tc = 1;

    hipMemsetAsync(d_ws, 0, stateBytes, stream);

    for (int t0 = 0; t0 < TLEN; t0 += Tc) {
        int t1 = t0 + Tc; if (t1 > TLEN) t1 = TLEN;
        lstm_l0<<<BATCH, 1024, 0, stream>>>(x, Wih0, Whh0, bih0, bhh0, h0, c0, y0, t0, t1);
        lstm_l1<<<BATCH, 1024, 0, stream>>>(y0, Wih1, Whh1, bih1, bhh1, h1, c1, t0, t1);
    }
    fc_kernel<<<BATCH, 128, 0, stream>>>(h1, Wfc, bfc, out);
}

// Round 3
// 911.980 us; speedup vs baseline: 1.7132x; 1.7132x over previous
//
#include <hip/hip_runtime.h>

#define BATCH 256
#define TLEN  512
#define DIN   64
#define HID   128
#define NGATE 512   // 4*HID
#define NOUT  40

typedef _Float16 f16x8 __attribute__((ext_vector_type(8)));
typedef _Float16 f16x4 __attribute__((ext_vector_type(4)));
typedef float    f32x4 __attribute__((ext_vector_type(4)));

static __device__ __forceinline__ f16x8 pack8(float4 a, float4 b) {
    f16x8 v;
    v[0] = (_Float16)a.x; v[1] = (_Float16)a.y; v[2] = (_Float16)a.z; v[3] = (_Float16)a.w;
    v[4] = (_Float16)b.x; v[5] = (_Float16)b.y; v[6] = (_Float16)b.z; v[7] = (_Float16)b.w;
    return v;
}

static __device__ __forceinline__ float sigmoidf_(float x) {
    return 1.0f / (1.0f + __expf(-x));
}
static __device__ __forceinline__ float tanhf_(float x) {
    float ax = fabsf(x);
    float e  = __expf(-2.0f * ax);
    float t  = (1.0f - e) / (1.0f + e);
    return copysignf(t, x);
}

// ================= Layer 0: x[b,t,0:64] -> y0[rel,b,0:128] (f16) =================
// One block per batch. 8 waves; wave w owns gates [w*64, w*64+64).
// Weights live in MFMA B-fragments (VGPRs): Wx 32 + Wh 64 regs per thread.
// A-fragment = x/h replicated across all 16 rows -> every C row equals the gate value.
__global__ void __attribute__((amdgpu_flat_work_group_size(512, 512), amdgpu_waves_per_eu(2, 2)))
lstm_l0(const float* __restrict__ x,
        const float* __restrict__ Wih, const float* __restrict__ Whh,
        const float* __restrict__ bih, const float* __restrict__ bhh,
        float* __restrict__ hstate, float* __restrict__ cstate,
        _Float16* __restrict__ y0, int t0, int t1)
{
    const int b    = blockIdx.x;
    const int tid  = threadIdx.x;
    const int lane = tid & 63;
    const int wave = tid >> 6;
    const int col  = lane & 15;   // gate index within 16-tile
    const int kg   = lane >> 4;   // k-slice group 0..3

    __shared__ __align__(16) _Float16 x_lds[2][DIN];
    __shared__ __align__(16) _Float16 h_lds[HID];
    __shared__ __align__(16) float    g_lds[NGATE];

    // ---- load B (weight) fragments once: k = kt*32 + kg*8 + j ----
    f16x8 Wx[4][2], Wh[4][4];
    #pragma unroll
    for (int t = 0; t < 4; ++t) {
        const int g = wave * 64 + t * 16 + col;
        #pragma unroll
        for (int kt = 0; kt < 2; ++kt) {
            const float* p = Wih + (size_t)g * DIN + kt * 32 + kg * 8;
            Wx[t][kt] = pack8(*(const float4*)p, *(const float4*)(p + 4));
        }
        #pragma unroll
        for (int kt = 0; kt < 4; ++kt) {
            const float* p = Whh + (size_t)g * HID + kt * 32 + kg * 8;
            Wh[t][kt] = pack8(*(const float4*)p, *(const float4*)(p + 4));
        }
    }

    float bi = 0.f, bf = 0.f, bg = 0.f, bo = 0.f, cc = 0.f, hr = 0.f;
    if (tid < HID) {
        bi = bih[tid]           + bhh[tid];
        bf = bih[tid + HID]     + bhh[tid + HID];
        bg = bih[tid + 2 * HID] + bhh[tid + 2 * HID];
        bo = bih[tid + 3 * HID] + bhh[tid + 3 * HID];
        cc = cstate[b * HID + tid];
        hr = hstate[b * HID + tid];
        h_lds[tid] = (_Float16)hr;
    }
    // stage x[t0]: 16 loader threads (wave 6), one float4 each
    const float4* xrow = (const float4*)(x + (size_t)b * TLEN * DIN);
    const int lk = tid - 384;
    if (lk >= 0 && lk < 16) {
        float4 v = xrow[(size_t)t0 * (DIN / 4) + lk];
        f16x4 p; p[0] = (_Float16)v.x; p[1] = (_Float16)v.y; p[2] = (_Float16)v.z; p[3] = (_Float16)v.w;
        *(f16x4*)&x_lds[0][lk * 4] = p;
    }
    __syncthreads();

    for (int t = t0; t < t1; ++t) {
        const int rel = t - t0, buf = rel & 1;
        // ---- phase A: fragments + MFMA + gate extraction ----
        f16x8 xa[2], ha[4];
        #pragma unroll
        for (int kt = 0; kt < 2; ++kt) xa[kt] = *(const f16x8*)&x_lds[buf][kt * 32 + kg * 8];
        #pragma unroll
        for (int kt = 0; kt < 4; ++kt) ha[kt] = *(const f16x8*)&h_lds[kt * 32 + kg * 8];

        float4 pf = make_float4(0.f, 0.f, 0.f, 0.f);
        if (lk >= 0 && lk < 16 && t + 1 < t1) pf = xrow[(size_t)(t + 1) * (DIN / 4) + lk];

        f32x4 a0 = {0.f,0.f,0.f,0.f}, a1 = a0, a2 = a0, a3 = a0;
        #pragma unroll
        for (int kt = 0; kt < 2; ++kt) {
            a0 = __builtin_amdgcn_mfma_f32_16x16x32_f16(xa[kt], Wx[0][kt], a0, 0, 0, 0);
            a1 = __builtin_amdgcn_mfma_f32_16x16x32_f16(xa[kt], Wx[1][kt], a1, 0, 0, 0);
            a2 = __builtin_amdgcn_mfma_f32_16x16x32_f16(xa[kt], Wx[2][kt], a2, 0, 0, 0);
            a3 = __builtin_amdgcn_mfma_f32_16x16x32_f16(xa[kt], Wx[3][kt], a3, 0, 0, 0);
        }
        #pragma unroll
        for (int kt = 0; kt < 4; ++kt) {
            a0 = __builtin_amdgcn_mfma_f32_16x16x32_f16(ha[kt], Wh[0][kt], a0, 0, 0, 0);
            a1 = __builtin_amdgcn_mfma_f32_16x16x32_f16(ha[kt], Wh[1][kt], a1, 0, 0, 0);
            a2 = __builtin_amdgcn_mfma_f32_16x16x32_f16(ha[kt], Wh[2][kt], a2, 0, 0, 0);
            a3 = __builtin_amdgcn_mfma_f32_16x16x32_f16(ha[kt], Wh[3][kt], a3, 0, 0, 0);
        }
        // all C rows identical; lane l takes tile (l>>4), col (l&15) -> gate = wave*64 + lane
        float gv = a0[0];
        gv = (kg == 1) ? a1[0] : gv;
        gv = (kg == 2) ? a2[0] : gv;
        gv = (kg == 3) ? a3[0] : gv;
        g_lds[wave * 64 + lane] = gv;
        __syncthreads();

        // ---- phase B: activations + cell update + staging writes ----
        if (tid < HID) {
            float gi = g_lds[tid] + bi;
            float gf = g_lds[tid + HID] + bf;
            float gg = g_lds[tid + 2 * HID] + bg;
            float go = g_lds[tid + 3 * HID] + bo;
            float iv = sigmoidf_(gi), fv = sigmoidf_(gf), gv2 = tanhf_(gg), ov = sigmoidf_(go);
            cc = fmaf(fv, cc, iv * gv2);
            hr = ov * tanhf_(cc);
            h_lds[tid] = (_Float16)hr;
            y0[((size_t)rel * BATCH + b) * HID + tid] = (_Float16)hr;
        }
        if (lk >= 0 && lk < 16 && t + 1 < t1) {
            f16x4 p; p[0] = (_Float16)pf.x; p[1] = (_Float16)pf.y; p[2] = (_Float16)pf.z; p[3] = (_Float16)pf.w;
            *(f16x4*)&x_lds[buf ^ 1][lk * 4] = p;
        }
        __syncthreads();
    }
    if (tid < HID) {
        cstate[b * HID + tid] = cc;
        hstate[b * HID + tid] = hr;
    }
}

// ================= Layer 1: y0[rel,b,0:128] (f16) -> h1/c1 =================
__global__ void __attribute__((amdgpu_flat_work_group_size(512, 512), amdgpu_waves_per_eu(2, 2)))
lstm_l1(const _Float16* __restrict__ y0,
        const float* __restrict__ Wih, const float* __restrict__ Whh,
        const float* __restrict__ bih, const float* __restrict__ bhh,
        float* __restrict__ hstate, float* __restrict__ cstate,
        int t0, int t1)
{
    const int b    = blockIdx.x;
    const int tid  = threadIdx.x;
    const int lane = tid & 63;
    const int wave = tid >> 6;
    const int col  = lane & 15;
    const int kg   = lane >> 4;

    __shared__ __align__(16) _Float16 y_lds[2][HID];
    __shared__ __align__(16) _Float16 h_lds[HID];
    __shared__ __align__(16) float    g_lds[NGATE];

    f16x8 Wy[4][4], Wh[4][4];
    #pragma unroll
    for (int t = 0; t < 4; ++t) {
        const int g = wave * 64 + t * 16 + col;
        #pragma unroll
        for (int kt = 0; kt < 4; ++kt) {
            const float* p = Wih + (size_t)g * HID + kt * 32 + kg * 8;
            Wy[t][kt] = pack8(*(const float4*)p, *(const float4*)(p + 4));
        }
        #pragma unroll
        for (int kt = 0; kt < 4; ++kt) {
            const float* p = Whh + (size_t)g * HID + kt * 32 + kg * 8;
            Wh[t][kt] = pack8(*(const float4*)p, *(const float4*)(p + 4));
        }
    }

    float bi = 0.f, bf = 0.f, bg = 0.f, bo = 0.f, cc = 0.f, hr = 0.f;
    if (tid < HID) {
        bi = bih[tid]           + bhh[tid];
        bf = bih[tid + HID]     + bhh[tid + HID];
        bg = bih[tid + 2 * HID] + bhh[tid + 2 * HID];
        bo = bih[tid + 3 * HID] + bhh[tid + 3 * HID];
        cc = cstate[b * HID + tid];
        hr = hstate[b * HID + tid];
        h_lds[tid] = (_Float16)hr;
    }
    // stage y0[t0]: 16 loaders copy uint4 (8 f16 each)
    const uint4* yrow = (const uint4*)y0;
    const int lk = tid - 384;
    if (lk >= 0 && lk < 16) {
        *(uint4*)&y_lds[0][lk * 8] = yrow[((size_t)0 * BATCH + b) * (HID / 8) + lk];
    }
    __syncthreads();

    for (int t = t0; t < t1; ++t) {
        const int rel = t - t0, buf = rel & 1;
        f16x8 ya[4], ha[4];
        #pragma unroll
        for (int kt = 0; kt < 4; ++kt) ya[kt] = *(const f16x8*)&y_lds[buf][kt * 32 + kg * 8];
        #pragma unroll
        for (int kt = 0; kt < 4; ++kt) ha[kt] = *(const f16x8*)&h_lds[kt * 32 + kg * 8];

        uint4 pf = make_uint4(0u, 0u, 0u, 0u);
        if (lk >= 0 && lk < 16 && t + 1 < t1)
            pf = yrow[((size_t)(rel + 1) * BATCH + b) * (HID / 8) + lk];

        f32x4 a0 = {0.f,0.f,0.f,0.f}, a1 = a0, a2 = a0, a3 = a0;
        #pragma unroll
        for (int kt = 0; kt < 4; ++kt) {
            a0 = __builtin_amdgcn_mfma_f32_16x16x32_f16(ya[kt], Wy[0][kt], a0, 0, 0, 0);
            a1 = __builtin_amdgcn_mfma_f32_16x16x32_f16(ya[kt], Wy[1][kt], a1, 0, 0, 0);
            a2 = __builtin_amdgcn_mfma_f32_16x16x32_f16(ya[kt], Wy[2][kt], a2, 0, 0, 0);
            a3 = __builtin_amdgcn_mfma_f32_16x16x32_f16(ya[kt], Wy[3][kt], a3, 0, 0, 0);
        }
        #pragma unroll
        for (int kt = 0; kt < 4; ++kt) {
            a0 = __builtin_amdgcn_mfma_f32_16x16x32_f16(ha[kt], Wh[0][kt], a0, 0, 0, 0);
            a1 = __builtin_amdgcn_mfma_f32_16x16x32_f16(ha[kt], Wh[1][kt], a1, 0, 0, 0);
            a2 = __builtin_amdgcn_mfma_f32_16x16x32_f16(ha[kt], Wh[2][kt], a2, 0, 0, 0);
            a3 = __builtin_amdgcn_mfma_f32_16x16x32_f16(ha[kt], Wh[3][kt], a3, 0, 0, 0);
        }
        float gv = a0[0];
        gv = (kg == 1) ? a1[0] : gv;
        gv = (kg == 2) ? a2[0] : gv;
        gv = (kg == 3) ? a3[0] : gv;
        g_lds[wave * 64 + lane] = gv;
        __syncthreads();

        if (tid < HID) {
            float gi = g_lds[tid] + bi;
            float gf = g_lds[tid + HID] + bf;
            float gg = g_lds[tid + 2 * HID] + bg;
            float go = g_lds[tid + 3 * HID] + bo;
            float iv = sigmoidf_(gi), fv = sigmoidf_(gf), gv2 = tanhf_(gg), ov = sigmoidf_(go);
            cc = fmaf(fv, cc, iv * gv2);
            hr = ov * tanhf_(cc);
            h_lds[tid] = (_Float16)hr;
        }
        if (lk >= 0 && lk < 16 && t + 1 < t1) {
            *(uint4*)&y_lds[buf ^ 1][lk * 8] = pf;
        }
        __syncthreads();
    }
    if (tid < HID) {
        cstate[b * HID + tid] = cc;
        hstate[b * HID + tid] = hr;
    }
}

// ================= Final FC =================
__global__ __launch_bounds__(128) void fc_kernel(
    const float* __restrict__ h1, const float* __restrict__ Wfc,
    const float* __restrict__ bfc, float* __restrict__ out)
{
    const int b = blockIdx.x;
    const int o = threadIdx.x;
    __shared__ float hs[HID];
    hs[o] = h1[b * HID + o];
    __syncthreads();
    if (o < NOUT) {
        const float4* w  = reinterpret_cast<const float4*>(Wfc + (size_t)o * HID);
        const float4* hv = reinterpret_cast<const float4*>(hs);
        float acc = bfc[o];
        #pragma unroll
        for (int q = 0; q < HID / 4; ++q) {
            float4 wv = w[q]; float4 h4 = hv[q];
            acc = fmaf(wv.x, h4.x, fmaf(wv.y, h4.y, fmaf(wv.z, h4.z, fmaf(wv.w, h4.w, acc))));
        }
        out[b * NOUT + o] = acc;
    }
}

extern "C" void kernel_launch(void* const* d_in, const int* in_sizes, int n_in,
                              void* d_out, int out_size, void* d_ws, size_t ws_size,
                              hipStream_t stream) {
    const float* x    = (const float*)d_in[0];
    const float* Wih0 = (const float*)d_in[1];
    const float* Whh0 = (const float*)d_in[2];
    const float* bih0 = (const float*)d_in[3];
    const float* bhh0 = (const float*)d_in[4];
    const float* Wih1 = (const float*)d_in[5];
    const float* Whh1 = (const float*)d_in[6];
    const float* bih1 = (const float*)d_in[7];
    const float* bhh1 = (const float*)d_in[8];
    const float* Wfc  = (const float*)d_in[9];
    const float* bfc  = (const float*)d_in[10];
    float* out = (float*)d_out;

    // Workspace: h0, c0, h1, c1 (f32) then y0 chunk slab (f16, [Tc][B][HID])
    float* h0 = (float*)d_ws;
    float* c0 = h0 + BATCH * HID;
    float* h1 = c0 + BATCH * HID;
    float* c1 = h1 + BATCH * HID;
    _Float16* y0 = (_Float16*)(c1 + BATCH * HID);

    const size_t stateBytes = (size_t)4 * BATCH * HID * sizeof(float);   // 512 KB
    size_t avail = ws_size > stateBytes ? ws_size - stateBytes : 0;
    int Tc = (int)(avail / ((size_t)BATCH * HID * sizeof(_Float16)));
    if (Tc > TLEN) Tc = TLEN;
    if (Tc < 1) Tc = 1;

    hipMemsetAsync(d_ws, 0, stateBytes, stream);

    for (int t0 = 0; t0 < TLEN; t0 += Tc) {
        int t1 = t0 + Tc; if (t1 > TLEN) t1 = TLEN;
        lstm_l0<<<BATCH, 512, 0, stream>>>(x, Wih0, Whh0, bih0, bhh0, h0, c0, y0, t0, t1);
        lstm_l1<<<BATCH, 512, 0, stream>>>(y0, Wih1, Whh1, bih1, bhh1, h1, c1, t0, t1);
    }
    fc_kernel<<<BATCH, 128, 0, stream>>>(h1, Wfc, bfc, out);
}